// Round 2
// baseline (102.538 us; speedup 1.0000x reference)
//
#include <hip/hip_runtime.h>

// RLS step: one 256-thread block per batch row b, 2 barriers total.
// Thread t owns 16 P elements: float4 #k at flat float4 index k*256+t
//   -> rows i = (t>>4) + 16k, cols 4*(t&15)..+3.  Coalesced 4KB/instr.
//
// Cross-thread data flow:
//   Px row sums : 16-lane shfl_xor butterfly (all lanes keep result -> g in reg)
//   denom       : from pre-reduction row partials, full-wave butterfly + 4 LDS scalars
//   xP col sums : shfl_xor(16,32) within wave + 4 wave-partials in LDS
//   y_hat/error : per-wave butterfly, redundant in all waves -> in-register everywhere

constexpr int T = 64;

__global__ __launch_bounds__(256) void rls_step(
    const float* __restrict__ x,       // (B,64)
    const float* __restrict__ d,       // (B,)
    const float* __restrict__ w_prev,  // (B,64)
    const float* __restrict__ P_prev,  // (B,64,64)
    const float* __restrict__ ffp,     // (1,)
    float* __restrict__ w_next,        // (B,64)
    float* __restrict__ P_next,        // (B,64,64)
    float* __restrict__ y_hat)         // (B,)
{
    const int b    = blockIdx.x;
    const int t    = threadIdx.x;   // 0..255
    const int wave = t >> 6;        // 0..3
    const int lane = t & 63;
    const int grp  = t >> 4;        // 0..15 ; rows grp + 16k
    const int sub  = t & 15;        // lane within row-group
    const int c0   = sub * 4;       // cols c0..c0+3

    __shared__ float  x_s[T];
    __shared__ float  w_s[T];
    __shared__ float  Px_s[T];
    __shared__ float4 xPw[4][16];   // per-wave xP partials
    __shared__ float  denw[4];      // per-wave denom partials

    const float lam     = fminf(fmaxf(ffp[0], 1.0e-4f), 0.9999f);
    const float inv_lam = 1.0f / lam;
    const float db      = d[b];     // wave-uniform -> scalar load

    const float4* __restrict__ Pv =
        reinterpret_cast<const float4*>(P_prev) + (size_t)b * (T * T / 4);
    float4* __restrict__ Pnv =
        reinterpret_cast<float4*>(P_next) + (size_t)b * (T * T / 4);

    // P loads in flight during LDS staging.
    float4 p0 = Pv[0 * 256 + t];
    float4 p1 = Pv[1 * 256 + t];
    float4 p2 = Pv[2 * 256 + t];
    float4 p3 = Pv[3 * 256 + t];

    if (t < 16)
        reinterpret_cast<float4*>(x_s)[t] =
            reinterpret_cast<const float4*>(x + (size_t)b * T)[t];
    else if (t < 32)
        reinterpret_cast<float4*>(w_s)[t - 16] =
            reinterpret_cast<const float4*>(w_prev + (size_t)b * T)[t - 16];
    __syncthreads();   // barrier 1

    const float xc0 = x_s[c0 + 0], xc1 = x_s[c0 + 1];
    const float xc2 = x_s[c0 + 2], xc3 = x_s[c0 + 3];
    const float xi0 = x_s[grp +  0];
    const float xi1 = x_s[grp + 16];
    const float xi2 = x_s[grp + 32];
    const float xi3 = x_s[grp + 48];

    // Row partial dots (over this thread's 4 columns).
    float r0 = p0.x * xc0 + p0.y * xc1 + p0.z * xc2 + p0.w * xc3;
    float r1 = p1.x * xc0 + p1.y * xc1 + p1.z * xc2 + p1.w * xc3;
    float r2 = p2.x * xc0 + p2.y * xc1 + p2.z * xc2 + p2.w * xc3;
    float r3 = p3.x * xc0 + p3.y * xc1 + p3.z * xc2 + p3.w * xc3;

    // denom partial = contribution of this thread's 16 elements to x^T P x.
    float dpart = xi0 * r0 + xi1 * r1 + xi2 * r2 + xi3 * r3;

    // y_hat partial (every wave computes the full reduction redundantly).
    float yp = w_s[lane] * x_s[lane];

    // Px: reduce over the 16 lanes sharing grp; ALL lanes keep the sums.
    r0 += __shfl_xor(r0, 1); r0 += __shfl_xor(r0, 2); r0 += __shfl_xor(r0, 4); r0 += __shfl_xor(r0, 8);
    r1 += __shfl_xor(r1, 1); r1 += __shfl_xor(r1, 2); r1 += __shfl_xor(r1, 4); r1 += __shfl_xor(r1, 8);
    r2 += __shfl_xor(r2, 1); r2 += __shfl_xor(r2, 2); r2 += __shfl_xor(r2, 4); r2 += __shfl_xor(r2, 8);
    r3 += __shfl_xor(r3, 1); r3 += __shfl_xor(r3, 2); r3 += __shfl_xor(r3, 4); r3 += __shfl_xor(r3, 8);
    if (sub == 0) {
        Px_s[grp +  0] = r0;
        Px_s[grp + 16] = r1;
        Px_s[grp + 32] = r2;
        Px_s[grp + 48] = r3;
    }

    // xP partials over this thread's 4 rows, then reduce the wave's 4 groups.
    float s0 = xi0 * p0.x + xi1 * p1.x + xi2 * p2.x + xi3 * p3.x;
    float s1 = xi0 * p0.y + xi1 * p1.y + xi2 * p2.y + xi3 * p3.y;
    float s2 = xi0 * p0.z + xi1 * p1.z + xi2 * p2.z + xi3 * p3.z;
    float s3 = xi0 * p0.w + xi1 * p1.w + xi2 * p2.w + xi3 * p3.w;
    s0 += __shfl_xor(s0, 16); s0 += __shfl_xor(s0, 32);
    s1 += __shfl_xor(s1, 16); s1 += __shfl_xor(s1, 32);
    s2 += __shfl_xor(s2, 16); s2 += __shfl_xor(s2, 32);
    s3 += __shfl_xor(s3, 16); s3 += __shfl_xor(s3, 32);
    if (lane < 16) xPw[wave][lane] = make_float4(s0, s1, s2, s3);

    // denom: full-wave butterfly.
    dpart += __shfl_xor(dpart, 1);  dpart += __shfl_xor(dpart, 2);
    dpart += __shfl_xor(dpart, 4);  dpart += __shfl_xor(dpart, 8);
    dpart += __shfl_xor(dpart, 16); dpart += __shfl_xor(dpart, 32);
    if (lane == 0) denw[wave] = dpart;

    // y_hat: full-wave butterfly (all lanes end with the sum).
    yp += __shfl_xor(yp, 1);  yp += __shfl_xor(yp, 2);
    yp += __shfl_xor(yp, 4);  yp += __shfl_xor(yp, 8);
    yp += __shfl_xor(yp, 16); yp += __shfl_xor(yp, 32);
    const float err = db - yp;

    __syncthreads();   // barrier 2

    const float inv_den = 1.0f / (lam + denw[0] + denw[1] + denw[2] + denw[3]);

    // Finish xP for this thread's 4 columns (broadcast float4 reads).
    const float4 q0 = xPw[0][sub], q1 = xPw[1][sub];
    const float4 q2 = xPw[2][sub], q3 = xPw[3][sub];
    const float xq0 = q0.x + q1.x + q2.x + q3.x;
    const float xq1 = q0.y + q1.y + q2.y + q3.y;
    const float xq2 = q0.z + q1.z + q2.z + q3.z;
    const float xq3 = q0.w + q1.w + q2.w + q3.w;

    // g at this thread's 4 rows -- still in-register from the butterfly.
    const float g0 = r0 * inv_den;
    const float g1 = r1 * inv_den;
    const float g2 = r2 * inv_den;
    const float g3 = r3 * inv_den;

    if (t < 64) {
        w_next[(size_t)b * T + t] = w_s[t] + Px_s[t] * inv_den * err;
    } else if (t == 64) {
        y_hat[b] = yp;
    }

    float4 o;
    o.x = (p0.x - g0 * xq0) * inv_lam;
    o.y = (p0.y - g0 * xq1) * inv_lam;
    o.z = (p0.z - g0 * xq2) * inv_lam;
    o.w = (p0.w - g0 * xq3) * inv_lam;
    Pnv[0 * 256 + t] = o;
    o.x = (p1.x - g1 * xq0) * inv_lam;
    o.y = (p1.y - g1 * xq1) * inv_lam;
    o.z = (p1.z - g1 * xq2) * inv_lam;
    o.w = (p1.w - g1 * xq3) * inv_lam;
    Pnv[1 * 256 + t] = o;
    o.x = (p2.x - g2 * xq0) * inv_lam;
    o.y = (p2.y - g2 * xq1) * inv_lam;
    o.z = (p2.z - g2 * xq2) * inv_lam;
    o.w = (p2.w - g2 * xq3) * inv_lam;
    Pnv[2 * 256 + t] = o;
    o.x = (p3.x - g3 * xq0) * inv_lam;
    o.y = (p3.y - g3 * xq1) * inv_lam;
    o.z = (p3.z - g3 * xq2) * inv_lam;
    o.w = (p3.w - g3 * xq3) * inv_lam;
    Pnv[3 * 256 + t] = o;
}

extern "C" void kernel_launch(void* const* d_in, const int* in_sizes, int n_in,
                              void* d_out, int out_size, void* d_ws, size_t ws_size,
                              hipStream_t stream) {
    const float* x      = (const float*)d_in[0];
    const float* d      = (const float*)d_in[1];
    const float* w_prev = (const float*)d_in[2];
    const float* P_prev = (const float*)d_in[3];
    const float* ffp    = (const float*)d_in[4];

    const int B = in_sizes[1];   // d has B elements

    float* out    = (float*)d_out;
    float* w_next = out;
    float* P_next = out + (size_t)B * T;
    float* y_hat  = out + (size_t)B * T + (size_t)B * T * T;

    rls_step<<<B, 256, 0, stream>>>(x, d, w_prev, P_prev, ffp,
                                    w_next, P_next, y_hat);
}